// Round 2
// baseline (1063.033 us; speedup 1.0000x reference)
//
#include <hip/hip_runtime.h>

static constexpr int NN = 100000;   // nodes
static constexpr int NE = 1600000;  // edges
static constexpr int NG = 1000;     // graphs
static constexpr int D  = 64;       // D_IN = D_HID
static constexpr int DH = 32;       // head hidden
static constexpr int DO = 8;        // out dim

// histogram: cnt[idx[i]] += 1
__global__ void k_count(const int* __restrict__ idx, int* __restrict__ cnt, int n) {
    int i = blockIdx.x * blockDim.x + threadIdx.x;
    if (i < n) atomicAdd(&cnt[idx[i]], 1);
}

// dinv = rsqrt(indeg + 1)  (self-loop makes deg >= 1 always)
__global__ void k_dinv(const int* __restrict__ deg, float* __restrict__ dinv, int n) {
    int i = blockIdx.x * blockDim.x + threadIdx.x;
    if (i < n) dinv[i] = rsqrtf((float)(deg[i] + 1));
}

// out[n][j] = dinv[n] * sum_k in[n][k] * W[k][j]    (W staged in LDS)
__global__ void k_mm_scale(const float* __restrict__ in, const float* __restrict__ W,
                           const float* __restrict__ dinv, float* __restrict__ out) {
    __shared__ float Ws[D * D];       // 16 KB
    __shared__ float rows[4][D];
    int t = threadIdx.x;              // 256 threads: 4 rows x 64 cols
    for (int i = t; i < D * D; i += 256) Ws[i] = W[i];
    int r = t >> 6, j = t & 63;
    int n = blockIdx.x * 4 + r;
    rows[r][j] = in[(long)n * D + j];   // NN % 4 == 0, always in range
    __syncthreads();
    float acc = 0.f;
#pragma unroll
    for (int k = 0; k < D; ++k) acc += rows[r][k] * Ws[k * D + j];
    out[(long)n * D + j] = acc * dinv[n];
}

// one wave per edge, lane = feature dim: acc[dst][d] += g[src][d]
__global__ void k_edge_agg(const int* __restrict__ src, const int* __restrict__ dst,
                           const float* __restrict__ g, float* __restrict__ acc) {
    int gid = blockIdx.x * blockDim.x + threadIdx.x;
    int e = gid >> 6;
    if (e >= NE) return;
    int d = gid & 63;
    int s = src[e], v = dst[e];
    atomicAdd(&acc[(long)v * D + d], g[(long)s * D + d]);
}

// g := relu((acc + g) * dinv[n] + b[d])     (self-loop term = g, folded here)
__global__ void k_post_relu(const float* __restrict__ accv, float* __restrict__ g,
                            const float* __restrict__ dinv, const float* __restrict__ b) {
    int i = blockIdx.x * blockDim.x + threadIdx.x;
    if (i >= NN * D) return;
    int n = i >> 6, d = i & 63;
    float v = (accv[i] + g[i]) * dinv[n] + b[d];
    g[i] = fmaxf(v, 0.f);
}

// layer-2 epilogue fused with mean-pool numerator: psum[batch[n]][d] += h2
__global__ void k_post_pool(const float* __restrict__ accv, const float* __restrict__ g,
                            const float* __restrict__ dinv, const float* __restrict__ b,
                            const int* __restrict__ batch, float* __restrict__ psum) {
    int i = blockIdx.x * blockDim.x + threadIdx.x;
    if (i >= NN * D) return;
    int n = i >> 6, d = i & 63;
    float v = (accv[i] + g[i]) * dinv[n] + b[d];
    atomicAdd(&psum[(long)batch[n] * D + d], v);
}

// per-graph head: mean, 64->32 relu, 32->8
__global__ void k_head(const float* __restrict__ psum, const int* __restrict__ cnt,
                       const float* __restrict__ lw1, const float* __restrict__ lb1,
                       const float* __restrict__ lw2, const float* __restrict__ lb2,
                       float* __restrict__ out) {
    __shared__ float pl[D];
    __shared__ float z[DH];
    int g = blockIdx.x;
    int t = threadIdx.x;  // 64
    float c = fmaxf((float)cnt[g], 1.0f);
    pl[t] = psum[(long)g * D + t] / c;
    __syncthreads();
    if (t < DH) {
        float a = lb1[t];
#pragma unroll
        for (int k = 0; k < D; ++k) a += pl[k] * lw1[k * DH + t];
        z[t] = fmaxf(a, 0.f);
    }
    __syncthreads();
    if (t < DO) {
        float a = lb2[t];
#pragma unroll
        for (int j = 0; j < DH; ++j) a += z[j] * lw2[j * DO + t];
        out[g * DO + t] = a;
    }
}

extern "C" void kernel_launch(void* const* d_in, const int* in_sizes, int n_in,
                              void* d_out, int out_size, void* d_ws, size_t ws_size,
                              hipStream_t stream) {
    const float* x    = (const float*)d_in[0];
    const int*   ei   = (const int*)  d_in[1];
    const int*   batch= (const int*)  d_in[2];
    const float* W1   = (const float*)d_in[3];
    const float* b1   = (const float*)d_in[4];
    const float* W2   = (const float*)d_in[5];
    const float* b2   = (const float*)d_in[6];
    const float* lw1  = (const float*)d_in[7];
    const float* lb1  = (const float*)d_in[8];
    const float* lw2  = (const float*)d_in[9];
    const float* lb2  = (const float*)d_in[10];
    float* out = (float*)d_out;

    const int* srcv = ei;        // edge_index[0]
    const int* dstv = ei + NE;   // edge_index[1]

    char* ws = (char*)d_ws;
    size_t off = 0;
    auto alloc = [&](size_t bytes) {
        void* p = ws + off;
        off = (off + bytes + 255) & ~(size_t)255;
        return p;
    };
    int*   deg  = (int*)  alloc((size_t)NN * 4);
    int*   cnt  = (int*)  alloc((size_t)NG * 4);
    float* dinv = (float*)alloc((size_t)NN * 4);
    float* psum = (float*)alloc((size_t)NG * D * 4);
    float* bufA = (float*)alloc((size_t)NN * D * 4);   // 25.6 MB
    float* bufB = (float*)alloc((size_t)NN * D * 4);   // 25.6 MB

    hipMemsetAsync(deg,  0, (size_t)NN * 4,     stream);
    hipMemsetAsync(cnt,  0, (size_t)NG * 4,     stream);
    hipMemsetAsync(psum, 0, (size_t)NG * D * 4, stream);
    hipMemsetAsync(bufB, 0, (size_t)NN * D * 4, stream);

    k_count<<<(NE + 255) / 256, 256, 0, stream>>>(dstv, deg, NE);
    k_count<<<(NN + 255) / 256, 256, 0, stream>>>(batch, cnt, NN);
    k_dinv <<<(NN + 255) / 256, 256, 0, stream>>>(deg, dinv, NN);

    // layer 1: g1 = (x @ W1) * dinv  -> bufA ; acc1 -> bufB
    k_mm_scale<<<NN / 4, 256, 0, stream>>>(x, W1, dinv, bufA);
    k_edge_agg<<<(NE * 64) / 256, 256, 0, stream>>>(srcv, dstv, bufA, bufB);
    k_post_relu<<<(NN * D) / 256, 256, 0, stream>>>(bufB, bufA, dinv, b1);  // bufA = h1

    // layer 2: g2 = (h1 @ W2) * dinv -> bufB ; acc2 -> bufA (zeroed after mm reads h1)
    k_mm_scale<<<NN / 4, 256, 0, stream>>>(bufA, W2, dinv, bufB);
    hipMemsetAsync(bufA, 0, (size_t)NN * D * 4, stream);
    k_edge_agg<<<(NE * 64) / 256, 256, 0, stream>>>(srcv, dstv, bufB, bufA);
    k_post_pool<<<(NN * D) / 256, 256, 0, stream>>>(bufA, bufB, dinv, b2, batch, psum);

    k_head<<<NG, 64, 0, stream>>>(psum, cnt, lw1, lb1, lw2, lb2, out);
}

// Round 3
// 551.492 us; speedup vs baseline: 1.9276x; 1.9276x over previous
//
#include <hip/hip_runtime.h>

static constexpr int NN = 100000;   // nodes
static constexpr int NE = 1600000;  // edges
static constexpr int NG = 1000;     // graphs
static constexpr int D  = 64;       // D_IN = D_HID
static constexpr int DH = 32;       // head hidden
static constexpr int DO = 8;        // out dim
static constexpr int NB = 391;      // ceil(NN/256) scan blocks
static constexpr int NPW = 8;       // nodes per wave in k_agg

// deg[dst[i]]++ and cnt[batch[i]]++ in one pass
__global__ void k_count2(const int* __restrict__ dst, const int* __restrict__ batch,
                         int* __restrict__ deg, int* __restrict__ cnt) {
    int i = blockIdx.x * 256 + threadIdx.x;
    if (i < NE) atomicAdd(&deg[dst[i]], 1);
    if (i < NN) atomicAdd(&cnt[batch[i]], 1);
}

// per-block sums of deg for the prefix scan
__global__ void k_blocksum(const int* __restrict__ deg, int* __restrict__ bsum) {
    __shared__ int ws[4];
    int i = blockIdx.x * 256 + threadIdx.x;
    int v = (i < NN) ? deg[i] : 0;
    for (int o = 32; o; o >>= 1) v += __shfl_down(v, o);
    if ((threadIdx.x & 63) == 0) ws[threadIdx.x >> 6] = v;
    __syncthreads();
    if (threadIdx.x == 0) bsum[blockIdx.x] = ws[0] + ws[1] + ws[2] + ws[3];
}

// single-block exclusive scan of the NB block sums
__global__ void k_scan_bsum(const int* __restrict__ bsum, int* __restrict__ boffs) {
    __shared__ int s[512];
    int t = threadIdx.x;
    int v = (t < NB) ? bsum[t] : 0;
    s[t] = v;
    __syncthreads();
    for (int o = 1; o < 512; o <<= 1) {
        int a = (t >= o) ? s[t - o] : 0;
        __syncthreads();
        s[t] += a;
        __syncthreads();
    }
    if (t < NB) boffs[t] = s[t] - v;   // exclusive
}

// rowptr = block-local exclusive scan + block offset; also cursor copy + dinv
__global__ void k_write_ptr(const int* __restrict__ deg, const int* __restrict__ boffs,
                            int* __restrict__ rowptr, int* __restrict__ cursor,
                            float* __restrict__ dinv) {
    __shared__ int s[256];
    int t = threadIdx.x, i = blockIdx.x * 256 + t;
    int d = (i < NN) ? deg[i] : 0;
    s[t] = d;
    __syncthreads();
    for (int o = 1; o < 256; o <<= 1) {
        int a = (t >= o) ? s[t - o] : 0;
        __syncthreads();
        s[t] += a;
        __syncthreads();
    }
    if (i < NN) {
        int excl = s[t] - d + boffs[blockIdx.x];
        rowptr[i] = excl;
        cursor[i] = excl;
        dinv[i]   = rsqrtf((float)(d + 1));
    }
    if (i == 0) rowptr[NN] = NE;
}

// scatter edges into CSR slots
__global__ void k_fill(const int* __restrict__ src, const int* __restrict__ dst,
                       int* __restrict__ cursor, int* __restrict__ csr) {
    int i = blockIdx.x * 256 + threadIdx.x;
    if (i < NE) {
        int slot = atomicAdd(&cursor[dst[i]], 1);
        csr[slot] = src[i];
    }
}

// out[n][j] = dinv[n] * sum_k in[n][k] * W[k][j]   (16 rows/block, 1024 thr)
__global__ void k_mm_scale(const float* __restrict__ in, const float* __restrict__ W,
                           const float* __restrict__ dinv, float* __restrict__ out) {
    __shared__ float Ws[D * D];       // 16 KB
    __shared__ float rows[16][D];
    int t = threadIdx.x;              // 1024 threads: 16 rows x 64 cols
    for (int i = t; i < D * D; i += 1024) Ws[i] = W[i];
    int r = t >> 6, j = t & 63;
    int n = blockIdx.x * 16 + r;      // NN % 16 == 0
    rows[r][j] = in[(long)n * D + j];
    __syncthreads();
    float acc = 0.f;
#pragma unroll
    for (int k = 0; k < D; ++k) acc += rows[r][k] * Ws[k * D + j];
    out[(long)n * D + j] = acc * dinv[n];
}

// CSR pull aggregation, epilogue fused. LAYER=1: h=relu(..)->out.
// LAYER=2: pooling partial sums flushed to psum on graph change.
template <int LAYER>
__global__ __launch_bounds__(256) void
k_agg(const int* __restrict__ rowptr, const int* __restrict__ csr,
      const float* __restrict__ g, const float* __restrict__ dinv,
      const float* __restrict__ bias, const int* __restrict__ batch,
      float* __restrict__ out, float* __restrict__ psum) {
    int lane = threadIdx.x & 63;
    int wid = (blockIdx.x << 2) + (threadIdx.x >> 6);
    wid = __builtin_amdgcn_readfirstlane(wid);
    int v0 = wid * NPW;
    if (v0 >= NN) return;
    int vend = min(v0 + NPW, NN);
    float bl = bias[lane];
    float pacc = 0.f;
    int pg = -1;
    for (int v = v0; v < vend; ++v) {
        int beg = rowptr[v], end = rowptr[v + 1];
        float s = g[(long)v * D + lane];            // self-loop term
        int e = beg;
        for (; e + 4 <= end; e += 4) {              // 4 gathers in flight
            int u0 = csr[e], u1 = csr[e + 1], u2 = csr[e + 2], u3 = csr[e + 3];
            float a0 = g[(long)u0 * D + lane];
            float a1 = g[(long)u1 * D + lane];
            float a2 = g[(long)u2 * D + lane];
            float a3 = g[(long)u3 * D + lane];
            s += a0; s += a1; s += a2; s += a3;
        }
        for (; e < end; ++e) s += g[(long)csr[e] * D + lane];
        float val = s * dinv[v] + bl;
        if (LAYER == 1) {
            out[(long)v * D + lane] = fmaxf(val, 0.f);
        } else {
            int bg = batch[v];
            if (bg != pg) {
                if (pg >= 0) atomicAdd(&psum[pg * D + lane], pacc);
                pacc = 0.f;
                pg = bg;
            }
            pacc += val;
        }
    }
    if (LAYER == 2 && pg >= 0) atomicAdd(&psum[pg * D + lane], pacc);
}

// per-graph head: mean, 64->32 relu, 32->8
__global__ void k_head(const float* __restrict__ psum, const int* __restrict__ cnt,
                       const float* __restrict__ lw1, const float* __restrict__ lb1,
                       const float* __restrict__ lw2, const float* __restrict__ lb2,
                       float* __restrict__ out) {
    __shared__ float pl[D];
    __shared__ float z[DH];
    int g = blockIdx.x;
    int t = threadIdx.x;  // 64
    float c = fmaxf((float)cnt[g], 1.0f);
    pl[t] = psum[(long)g * D + t] / c;
    __syncthreads();
    if (t < DH) {
        float a = lb1[t];
#pragma unroll
        for (int k = 0; k < D; ++k) a += pl[k] * lw1[k * DH + t];
        z[t] = fmaxf(a, 0.f);
    }
    __syncthreads();
    if (t < DO) {
        float a = lb2[t];
#pragma unroll
        for (int j = 0; j < DH; ++j) a += z[j] * lw2[j * DO + t];
        out[g * DO + t] = a;
    }
}

extern "C" void kernel_launch(void* const* d_in, const int* in_sizes, int n_in,
                              void* d_out, int out_size, void* d_ws, size_t ws_size,
                              hipStream_t stream) {
    const float* x    = (const float*)d_in[0];
    const int*   ei   = (const int*)  d_in[1];
    const int*   batch= (const int*)  d_in[2];
    const float* W1   = (const float*)d_in[3];
    const float* b1   = (const float*)d_in[4];
    const float* W2   = (const float*)d_in[5];
    const float* b2   = (const float*)d_in[6];
    const float* lw1  = (const float*)d_in[7];
    const float* lb1  = (const float*)d_in[8];
    const float* lw2  = (const float*)d_in[9];
    const float* lb2  = (const float*)d_in[10];
    float* out = (float*)d_out;

    const int* srcv = ei;        // edge_index[0]
    const int* dstv = ei + NE;   // edge_index[1]

    char* ws = (char*)d_ws;
    size_t off = 0;
    auto alloc = [&](size_t bytes) {
        void* p = ws + off;
        off = (off + bytes + 255) & ~(size_t)255;
        return p;
    };
    int*   deg    = (int*)  alloc((size_t)NN * 4);
    int*   cnt    = (int*)  alloc((size_t)NG * 4);
    int*   bsum   = (int*)  alloc((size_t)NB * 4);
    int*   boffs  = (int*)  alloc((size_t)NB * 4);
    int*   rowptr = (int*)  alloc((size_t)(NN + 1) * 4);
    int*   cursor = (int*)  alloc((size_t)NN * 4);
    int*   csr    = (int*)  alloc((size_t)NE * 4);      // 6.4 MB
    float* dinv   = (float*)alloc((size_t)NN * 4);
    float* psum   = (float*)alloc((size_t)NG * D * 4);
    float* bufA   = (float*)alloc((size_t)NN * D * 4);  // 25.6 MB
    float* bufB   = (float*)alloc((size_t)NN * D * 4);  // 25.6 MB

    hipMemsetAsync(deg,  0, (size_t)NN * 4,     stream);
    hipMemsetAsync(cnt,  0, (size_t)NG * 4,     stream);
    hipMemsetAsync(psum, 0, (size_t)NG * D * 4, stream);

    k_count2   <<<(NE + 255) / 256, 256, 0, stream>>>(dstv, batch, deg, cnt);
    k_blocksum <<<NB, 256, 0, stream>>>(deg, bsum);
    k_scan_bsum<<<1, 512, 0, stream>>>(bsum, boffs);
    k_write_ptr<<<NB, 256, 0, stream>>>(deg, boffs, rowptr, cursor, dinv);
    k_fill     <<<(NE + 255) / 256, 256, 0, stream>>>(srcv, dstv, cursor, csr);

    // layer 1: g1 = (x @ W1) * dinv -> bufA ; h1 = relu(agg) -> bufB
    k_mm_scale<<<NN / 16, 1024, 0, stream>>>(x, W1, dinv, bufA);
    k_agg<1><<<(NN + 4 * NPW - 1) / (4 * NPW), 256, 0, stream>>>(
        rowptr, csr, bufA, dinv, b1, batch, bufB, nullptr);

    // layer 2: g2 = (h1 @ W2) * dinv -> bufA ; agg + pool -> psum
    k_mm_scale<<<NN / 16, 1024, 0, stream>>>(bufB, W2, dinv, bufA);
    k_agg<2><<<(NN + 4 * NPW - 1) / (4 * NPW), 256, 0, stream>>>(
        rowptr, csr, bufA, dinv, b2, batch, nullptr, psum);

    k_head<<<NG, 64, 0, stream>>>(psum, cnt, lw1, lb1, lw2, lb2, out);
}